// Round 1
// baseline (871.987 us; speedup 1.0000x reference)
//
#include <hip/hip_runtime.h>
#include <hip/hip_bf16.h>
#include <math.h>

// ---------------------------------------------------------------------------
// GCN: 3x GCNConv(128->128) + fused (Wp1@Wp2) head + log_softmax. fp32.
// Strategy:
//   - Build dst-grouped CSR once per call (atomic range allocation; order of
//     ranges is irrelevant, only disjointness).
//   - h_scaled = (h @ W) * norm[row]  (GEMM epilogue), so
//     layer_out = relu(norm[i]*(sum_{in} h_scaled[src] + h_scaled[i]) + b).
//   - Head: Wf = Wp1@Wp2 (128x40), bf = bp1@Wp2 + bp2, fused with log_softmax.
// ---------------------------------------------------------------------------

#define DH 128   // feature dim (D == H == 128)
#define NC 40    // classes

// ---------------- degree / norm / CSR ----------------

__global__ __launch_bounds__(256) void count_deg(const int* __restrict__ dst, int E,
                                                 unsigned* __restrict__ cnt) {
    int e = blockIdx.x * 256 + threadIdx.x;
    if (e < E) atomicAdd(&cnt[dst[e]], 1u);
}

__global__ __launch_bounds__(256) void norm_off(const unsigned* __restrict__ cnt,
                                                float* __restrict__ nrm,
                                                unsigned* __restrict__ off,
                                                unsigned* __restrict__ cur,
                                                unsigned* __restrict__ cursor, int N) {
    int i = blockIdx.x * 256 + threadIdx.x;
    if (i < N) {
        unsigned d = cnt[i];
        nrm[i] = rsqrtf((float)d + 1.0f);
        off[i] = atomicAdd(cursor, d);   // disjoint range per node; order irrelevant
        cur[i] = 0u;
    }
}

__global__ __launch_bounds__(256) void fill_csr(const int* __restrict__ src,
                                                const int* __restrict__ dst, int E,
                                                const unsigned* __restrict__ off,
                                                unsigned* __restrict__ cur,
                                                int* __restrict__ csr) {
    int e = blockIdx.x * 256 + threadIdx.x;
    if (e < E) {
        int d = dst[e];
        unsigned p = off[d] + atomicAdd(&cur[d], 1u);
        csr[p] = src[e];
    }
}

// ---------------- head weight fusion: Wf = Wp1@Wp2, bf = bp1@Wp2 + bp2 ------

__global__ __launch_bounds__(256) void fuse_w(const float* __restrict__ Wp1,
                                              const float* __restrict__ bp1,
                                              const float* __restrict__ Wp2,
                                              const float* __restrict__ bp2,
                                              float* __restrict__ Wf,
                                              float* __restrict__ bf) {
    int o = blockIdx.x * 256 + threadIdx.x;
    if (o < DH * NC) {
        int k = o / NC, c = o - k * NC;
        float acc = 0.f;
        for (int j = 0; j < DH; ++j) acc += Wp1[k * DH + j] * Wp2[j * NC + c];
        Wf[o] = acc;
    } else if (o < DH * NC + NC) {
        int c = o - DH * NC;
        float acc = bp2[c];
        for (int j = 0; j < DH; ++j) acc += bp1[j] * Wp2[j * NC + c];
        bf[c] = acc;
    }
}

// ---------------- GEMM (NxDH @ DHxDH) with per-row norm scaling -------------
// BM=64, BN=128, BK=32, 256 threads, thread microtile 4 rows x (4+4) cols.

__global__ __launch_bounds__(256) void gemm_scale(const float* __restrict__ X,
                                                  const float* __restrict__ W,
                                                  const float* __restrict__ nrm,
                                                  float* __restrict__ out, int nrows) {
    __shared__ float xs[64][36];    // pad to 36: 16B-aligned rows, 2-way bank alias (free)
    __shared__ float ws[32][128];

    const int tid = threadIdx.x;
    const int tx = tid & 15;        // col group: cols tx*4..+3 and 64+tx*4..+3
    const int ty = tid >> 4;        // row group: rows ty*4..+3
    const int rbase = blockIdx.x * 64;

    float acc[4][8];
#pragma unroll
    for (int i = 0; i < 4; ++i)
#pragma unroll
        for (int j = 0; j < 8; ++j) acc[i][j] = 0.f;

    const int lrow = tid >> 2;            // 0..63
    const int lcol = (tid & 3) * 8;       // 0,8,16,24

    for (int kk = 0; kk < DH; kk += 32) {
        // stage x chunk: 64 rows x 32 k
        {
            float4 v0 = make_float4(0.f, 0.f, 0.f, 0.f), v1 = v0;
            int gr = rbase + lrow;
            if (gr < nrows) {
                const float* p = X + (size_t)gr * DH + kk + lcol;
                v0 = *(const float4*)p;
                v1 = *(const float4*)(p + 4);
            }
            *(float4*)&xs[lrow][lcol]     = v0;
            *(float4*)&xs[lrow][lcol + 4] = v1;
        }
        // stage W chunk: 32 k x 128 cols
        {
            int krow = tid >> 3;              // 0..31
            int c    = (tid & 7) * 16;        // 0..112
            const float* p = W + (size_t)(kk + krow) * DH + c;
            *(float4*)&ws[krow][c]      = *(const float4*)(p);
            *(float4*)&ws[krow][c + 4]  = *(const float4*)(p + 4);
            *(float4*)&ws[krow][c + 8]  = *(const float4*)(p + 8);
            *(float4*)&ws[krow][c + 12] = *(const float4*)(p + 12);
        }
        __syncthreads();

#pragma unroll
        for (int k = 0; k < 32; ++k) {
            float a0 = xs[ty * 4 + 0][k];
            float a1 = xs[ty * 4 + 1][k];
            float a2 = xs[ty * 4 + 2][k];
            float a3 = xs[ty * 4 + 3][k];
            float4 w0 = *(float4*)&ws[k][tx * 4];
            float4 w1 = *(float4*)&ws[k][64 + tx * 4];
            acc[0][0] += a0 * w0.x; acc[0][1] += a0 * w0.y; acc[0][2] += a0 * w0.z; acc[0][3] += a0 * w0.w;
            acc[0][4] += a0 * w1.x; acc[0][5] += a0 * w1.y; acc[0][6] += a0 * w1.z; acc[0][7] += a0 * w1.w;
            acc[1][0] += a1 * w0.x; acc[1][1] += a1 * w0.y; acc[1][2] += a1 * w0.z; acc[1][3] += a1 * w0.w;
            acc[1][4] += a1 * w1.x; acc[1][5] += a1 * w1.y; acc[1][6] += a1 * w1.z; acc[1][7] += a1 * w1.w;
            acc[2][0] += a2 * w0.x; acc[2][1] += a2 * w0.y; acc[2][2] += a2 * w0.z; acc[2][3] += a2 * w0.w;
            acc[2][4] += a2 * w1.x; acc[2][5] += a2 * w1.y; acc[2][6] += a2 * w1.z; acc[2][7] += a2 * w1.w;
            acc[3][0] += a3 * w0.x; acc[3][1] += a3 * w0.y; acc[3][2] += a3 * w0.z; acc[3][3] += a3 * w0.w;
            acc[3][4] += a3 * w1.x; acc[3][5] += a3 * w1.y; acc[3][6] += a3 * w1.z; acc[3][7] += a3 * w1.w;
        }
        __syncthreads();
    }

#pragma unroll
    for (int i = 0; i < 4; ++i) {
        int r = rbase + ty * 4 + i;
        if (r < nrows) {
            float s = nrm[r];
            float4 o0 = make_float4(acc[i][0] * s, acc[i][1] * s, acc[i][2] * s, acc[i][3] * s);
            float4 o1 = make_float4(acc[i][4] * s, acc[i][5] * s, acc[i][6] * s, acc[i][7] * s);
            *(float4*)(out + (size_t)r * DH + tx * 4)      = o0;
            *(float4*)(out + (size_t)r * DH + 64 + tx * 4) = o1;
        }
    }
}

// ---------------- CSR aggregation: B = relu(norm*(sum A[src] + A[i]) + b) ---
// 32 lanes per node, float4 per lane (128 cols). 8 nodes per 256-thread block.

__global__ __launch_bounds__(256) void aggregate(const float* __restrict__ A,
                                                 const int* __restrict__ csr,
                                                 const unsigned* __restrict__ off,
                                                 const unsigned* __restrict__ cnt,
                                                 const float* __restrict__ nrm,
                                                 const float* __restrict__ bias,
                                                 float* __restrict__ B, int N) {
    int node = blockIdx.x * 8 + (threadIdx.x >> 5);
    int lane = threadIdx.x & 31;
    if (node >= N) return;

    const float4* Av = (const float4*)A;
    float4 acc = Av[(size_t)node * 32 + lane];   // self term
    unsigned o = off[node];
    unsigned d = cnt[node];

    unsigned e = 0;
    for (; e + 4 <= d; e += 4) {
        int s0 = csr[o + e + 0];
        int s1 = csr[o + e + 1];
        int s2 = csr[o + e + 2];
        int s3 = csr[o + e + 3];
        float4 v0 = Av[(size_t)s0 * 32 + lane];
        float4 v1 = Av[(size_t)s1 * 32 + lane];
        float4 v2 = Av[(size_t)s2 * 32 + lane];
        float4 v3 = Av[(size_t)s3 * 32 + lane];
        acc.x += v0.x + v1.x + v2.x + v3.x;
        acc.y += v0.y + v1.y + v2.y + v3.y;
        acc.z += v0.z + v1.z + v2.z + v3.z;
        acc.w += v0.w + v1.w + v2.w + v3.w;
    }
    for (; e < d; ++e) {
        int s = csr[o + e];
        float4 v = Av[(size_t)s * 32 + lane];
        acc.x += v.x; acc.y += v.y; acc.z += v.z; acc.w += v.w;
    }

    float nm = nrm[node];
    float4 b4 = *(const float4*)(bias + lane * 4);
    float4 r;
    r.x = fmaxf(acc.x * nm + b4.x, 0.f);
    r.y = fmaxf(acc.y * nm + b4.y, 0.f);
    r.z = fmaxf(acc.z * nm + b4.z, 0.f);
    r.w = fmaxf(acc.w * nm + b4.w, 0.f);
    ((float4*)B)[(size_t)node * 32 + lane] = r;
}

// ---------------- final: logits = X @ Wf + bf; out = log_softmax ------------
// 32 rows per 256-thread block.

__global__ __launch_bounds__(256) void final_kernel(const float* __restrict__ X,
                                                    const float* __restrict__ Wf,
                                                    const float* __restrict__ bf,
                                                    float* __restrict__ out, int nrows) {
    __shared__ float xs[32][129];
    __shared__ float wf[DH * NC];
    __shared__ float ls[32][NC + 1];
    __shared__ float mrow[32], srow[32];

    const int tid = threadIdx.x;
    const int base = blockIdx.x * 32;

    for (int i = tid; i < DH * NC; i += 256) wf[i] = Wf[i];
    for (int i = tid * 4; i < 32 * DH; i += 1024) {
        int r = i >> 7, c = i & 127;
        int gr = base + r;
        float4 v = make_float4(0.f, 0.f, 0.f, 0.f);
        if (gr < nrows) v = *(const float4*)(X + (size_t)gr * DH + c);
        xs[r][c] = v.x; xs[r][c + 1] = v.y; xs[r][c + 2] = v.z; xs[r][c + 3] = v.w;
    }
    __syncthreads();

    for (int o = tid; o < 32 * NC; o += 256) {
        int r = o / NC, c = o - r * NC;
        float acc = bf[c];
#pragma unroll 8
        for (int k = 0; k < DH; ++k) acc += xs[r][k] * wf[k * NC + c];
        ls[r][c] = acc;
    }
    __syncthreads();

    if (tid < 32) {
        float m = -1e30f;
        for (int c = 0; c < NC; ++c) m = fmaxf(m, ls[tid][c]);
        float s = 0.f;
        for (int c = 0; c < NC; ++c) s += expf(ls[tid][c] - m);
        mrow[tid] = m;
        srow[tid] = logf(s);
    }
    __syncthreads();

    for (int o = tid; o < 32 * NC; o += 256) {
        int r = o / NC, c = o - r * NC;
        int gr = base + r;
        if (gr < nrows) out[(size_t)gr * NC + c] = ls[r][c] - mrow[r] - srow[r];
    }
}

// ---------------------------------------------------------------------------

extern "C" void kernel_launch(void* const* d_in, const int* in_sizes, int n_in,
                              void* d_out, int out_size, void* d_ws, size_t ws_size,
                              hipStream_t stream) {
    const float* x   = (const float*)d_in[0];
    const int*   ei  = (const int*)d_in[1];
    const float* W1  = (const float*)d_in[2];
    const float* b1  = (const float*)d_in[3];
    const float* W2  = (const float*)d_in[4];
    const float* b2  = (const float*)d_in[5];
    const float* W3  = (const float*)d_in[6];
    const float* b3  = (const float*)d_in[7];
    const float* Wp1 = (const float*)d_in[8];
    const float* bp1 = (const float*)d_in[9];
    const float* Wp2 = (const float*)d_in[10];
    const float* bp2 = (const float*)d_in[11];
    float* out = (float*)d_out;

    const int N = in_sizes[0] / DH;
    const int E = in_sizes[1] / 2;
    const int* src = ei;
    const int* dst = ei + E;

    // workspace carve (all 16B aligned)
    char* w = (char*)d_ws;
    float*    A      = (float*)w;  w += (size_t)N * DH * 4;
    float*    Bf     = (float*)w;  w += (size_t)N * DH * 4;
    int*      csr    = (int*)w;    w += (size_t)E * 4;
    unsigned* cnt    = (unsigned*)w; w += (size_t)N * 4;
    unsigned* cursor = (unsigned*)w; w += 16;
    unsigned* off    = (unsigned*)w; w += (size_t)N * 4;
    unsigned* cur    = (unsigned*)w; w += (size_t)N * 4;
    float*    nrm    = (float*)w;  w += (size_t)N * 4;
    float*    Wf     = (float*)w;  w += DH * NC * 4;
    float*    bfz    = (float*)w;  w += 256;

    const int gE = (E + 255) / 256;
    const int gN = (N + 255) / 256;

    hipMemsetAsync(cnt, 0, (size_t)N * 4 + 16, stream);  // cnt + cursor
    count_deg<<<gE, 256, 0, stream>>>(dst, E, cnt);
    norm_off<<<gN, 256, 0, stream>>>(cnt, nrm, off, cur, cursor, N);
    fill_csr<<<gE, 256, 0, stream>>>(src, dst, E, off, cur, csr);
    fuse_w<<<(DH * NC + NC + 255) / 256, 256, 0, stream>>>(Wp1, bp1, Wp2, bp2, Wf, bfz);

    const int gG = (N + 63) / 64;
    const int gA = (N + 7) / 8;

    gemm_scale<<<gG, 256, 0, stream>>>(x,  W1, nrm, A,  N);
    aggregate <<<gA, 256, 0, stream>>>(A, csr, off, cnt, nrm, b1, Bf, N);
    gemm_scale<<<gG, 256, 0, stream>>>(Bf, W2, nrm, A,  N);
    aggregate <<<gA, 256, 0, stream>>>(A, csr, off, cnt, nrm, b2, Bf, N);
    gemm_scale<<<gG, 256, 0, stream>>>(Bf, W3, nrm, A,  N);
    aggregate <<<gA, 256, 0, stream>>>(A, csr, off, cnt, nrm, b3, Bf, N);

    final_kernel<<<(N + 31) / 32, 256, 0, stream>>>(Bf, Wf, bfz, out, N);
}

// Round 2
// 746.160 us; speedup vs baseline: 1.1686x; 1.1686x over previous
//
#include <hip/hip_runtime.h>
#include <hip/hip_bf16.h>
#include <math.h>

// ---------------------------------------------------------------------------
// GCN: 3x GCNConv(128->128) + fused (Wp1@Wp2) head + log_softmax.
// Round 2: bf16 gather buffer (halves aggregate traffic), single-atomic CSR
// fill (2 random ops/edge instead of 3).
//   - h_scaled = bf16((h @ W) * norm[row])  (GEMM epilogue)
//   - layer_out = relu(norm[i]*(sum_{in} h_scaled[src] + h_scaled[i]) + b), fp32 accum
// ---------------------------------------------------------------------------

#define DH 128   // feature dim (D == H == 128)
#define NC 40    // classes

__device__ __forceinline__ unsigned short f2bf(float f) {
    unsigned u = __float_as_uint(f);
    unsigned r = (u + 0x7fffu + ((u >> 16) & 1u)) >> 16;   // RNE
    return (unsigned short)r;
}

// ---------------- degree / norm / CSR ----------------

__global__ __launch_bounds__(256) void count_deg(const int* __restrict__ dst, int E,
                                                 unsigned* __restrict__ cnt) {
    int e = blockIdx.x * 256 + threadIdx.x;
    if (e < E) atomicAdd(&cnt[dst[e]], 1u);
}

__global__ __launch_bounds__(256) void norm_off(const unsigned* __restrict__ cnt,
                                                float* __restrict__ nrm,
                                                unsigned* __restrict__ off,
                                                unsigned* __restrict__ pos,
                                                unsigned* __restrict__ cursor, int N) {
    int i = blockIdx.x * 256 + threadIdx.x;
    if (i < N) {
        unsigned d = cnt[i];
        nrm[i] = rsqrtf((float)d + 1.0f);
        unsigned o = atomicAdd(cursor, d);   // disjoint range per node; order irrelevant
        off[i] = o;
        pos[i] = o;
    }
}

__global__ __launch_bounds__(256) void fill_csr(const int* __restrict__ src,
                                                const int* __restrict__ dst, int E,
                                                unsigned* __restrict__ pos,
                                                int* __restrict__ csr) {
    int e = blockIdx.x * 256 + threadIdx.x;
    if (e < E) {
        unsigned p = atomicAdd(&pos[dst[e]], 1u);
        csr[p] = src[e];
    }
}

// ---------------- head weight fusion: Wf = Wp1@Wp2, bf = bp1@Wp2 + bp2 ------

__global__ __launch_bounds__(256) void fuse_w(const float* __restrict__ Wp1,
                                              const float* __restrict__ bp1,
                                              const float* __restrict__ Wp2,
                                              const float* __restrict__ bp2,
                                              float* __restrict__ Wf,
                                              float* __restrict__ bf) {
    int o = blockIdx.x * 256 + threadIdx.x;
    if (o < DH * NC) {
        int k = o / NC, c = o - k * NC;
        float acc = 0.f;
        for (int j = 0; j < DH; ++j) acc += Wp1[k * DH + j] * Wp2[j * NC + c];
        Wf[o] = acc;
    } else if (o < DH * NC + NC) {
        int c = o - DH * NC;
        float acc = bp2[c];
        for (int j = 0; j < DH; ++j) acc += bp1[j] * Wp2[j * NC + c];
        bf[c] = acc;
    }
}

// ---------------- GEMM (NxDH @ DHxDH), epilogue: *norm[row] -> bf16 ---------
// BM=64, BN=128, BK=32, 256 threads, thread microtile 4 rows x (4+4) cols.

__global__ __launch_bounds__(256) void gemm_scale(const float* __restrict__ X,
                                                  const float* __restrict__ W,
                                                  const float* __restrict__ nrm,
                                                  unsigned short* __restrict__ outb,
                                                  int nrows) {
    __shared__ float xs[64][36];    // pad to 36: 16B-aligned rows, 2-way bank alias (free)
    __shared__ float ws[32][128];

    const int tid = threadIdx.x;
    const int tx = tid & 15;        // col group: cols tx*4..+3 and 64+tx*4..+3
    const int ty = tid >> 4;        // row group: rows ty*4..+3
    const int rbase = blockIdx.x * 64;

    float acc[4][8];
#pragma unroll
    for (int i = 0; i < 4; ++i)
#pragma unroll
        for (int j = 0; j < 8; ++j) acc[i][j] = 0.f;

    const int lrow = tid >> 2;            // 0..63
    const int lcol = (tid & 3) * 8;       // 0,8,16,24

    for (int kk = 0; kk < DH; kk += 32) {
        {
            float4 v0 = make_float4(0.f, 0.f, 0.f, 0.f), v1 = v0;
            int gr = rbase + lrow;
            if (gr < nrows) {
                const float* p = X + (size_t)gr * DH + kk + lcol;
                v0 = *(const float4*)p;
                v1 = *(const float4*)(p + 4);
            }
            *(float4*)&xs[lrow][lcol]     = v0;
            *(float4*)&xs[lrow][lcol + 4] = v1;
        }
        {
            int krow = tid >> 3;              // 0..31
            int c    = (tid & 7) * 16;        // 0..112
            const float* p = W + (size_t)(kk + krow) * DH + c;
            *(float4*)&ws[krow][c]      = *(const float4*)(p);
            *(float4*)&ws[krow][c + 4]  = *(const float4*)(p + 4);
            *(float4*)&ws[krow][c + 8]  = *(const float4*)(p + 8);
            *(float4*)&ws[krow][c + 12] = *(const float4*)(p + 12);
        }
        __syncthreads();

#pragma unroll
        for (int k = 0; k < 32; ++k) {
            float a0 = xs[ty * 4 + 0][k];
            float a1 = xs[ty * 4 + 1][k];
            float a2 = xs[ty * 4 + 2][k];
            float a3 = xs[ty * 4 + 3][k];
            float4 w0 = *(float4*)&ws[k][tx * 4];
            float4 w1 = *(float4*)&ws[k][64 + tx * 4];
            acc[0][0] += a0 * w0.x; acc[0][1] += a0 * w0.y; acc[0][2] += a0 * w0.z; acc[0][3] += a0 * w0.w;
            acc[0][4] += a0 * w1.x; acc[0][5] += a0 * w1.y; acc[0][6] += a0 * w1.z; acc[0][7] += a0 * w1.w;
            acc[1][0] += a1 * w0.x; acc[1][1] += a1 * w0.y; acc[1][2] += a1 * w0.z; acc[1][3] += a1 * w0.w;
            acc[1][4] += a1 * w1.x; acc[1][5] += a1 * w1.y; acc[1][6] += a1 * w1.z; acc[1][7] += a1 * w1.w;
            acc[2][0] += a2 * w0.x; acc[2][1] += a2 * w0.y; acc[2][2] += a2 * w0.z; acc[2][3] += a2 * w0.w;
            acc[2][4] += a2 * w1.x; acc[2][5] += a2 * w1.y; acc[2][6] += a2 * w1.z; acc[2][7] += a2 * w1.w;
            acc[3][0] += a3 * w0.x; acc[3][1] += a3 * w0.y; acc[3][2] += a3 * w0.z; acc[3][3] += a3 * w0.w;
            acc[3][4] += a3 * w1.x; acc[3][5] += a3 * w1.y; acc[3][6] += a3 * w1.z; acc[3][7] += a3 * w1.w;
        }
        __syncthreads();
    }

#pragma unroll
    for (int i = 0; i < 4; ++i) {
        int r = rbase + ty * 4 + i;
        if (r < nrows) {
            float s = nrm[r];
            ushort4 o0, o1;
            o0.x = f2bf(acc[i][0] * s); o0.y = f2bf(acc[i][1] * s);
            o0.z = f2bf(acc[i][2] * s); o0.w = f2bf(acc[i][3] * s);
            o1.x = f2bf(acc[i][4] * s); o1.y = f2bf(acc[i][5] * s);
            o1.z = f2bf(acc[i][6] * s); o1.w = f2bf(acc[i][7] * s);
            *(ushort4*)(outb + (size_t)r * DH + tx * 4)      = o0;
            *(ushort4*)(outb + (size_t)r * DH + 64 + tx * 4) = o1;
        }
    }
}

// ---------------- CSR aggregation: B = relu(norm*(sum Abf[src] + Abf[i]) + b)
// 16 lanes per node, 16B (8 bf16) per lane. 16 nodes per 256-thread block.

__device__ __forceinline__ void bf8_add(float* acc, uint4 v) {
    acc[0] += __uint_as_float(v.x << 16);
    acc[1] += __uint_as_float(v.x & 0xffff0000u);
    acc[2] += __uint_as_float(v.y << 16);
    acc[3] += __uint_as_float(v.y & 0xffff0000u);
    acc[4] += __uint_as_float(v.z << 16);
    acc[5] += __uint_as_float(v.z & 0xffff0000u);
    acc[6] += __uint_as_float(v.w << 16);
    acc[7] += __uint_as_float(v.w & 0xffff0000u);
}

__global__ __launch_bounds__(256) void aggregate(const uint4* __restrict__ Abf,
                                                 const int* __restrict__ csr,
                                                 const unsigned* __restrict__ off,
                                                 const unsigned* __restrict__ cnt,
                                                 const float* __restrict__ nrm,
                                                 const float* __restrict__ bias,
                                                 float* __restrict__ B, int N) {
    int node = blockIdx.x * 16 + (threadIdx.x >> 4);
    int lane = threadIdx.x & 15;
    if (node >= N) return;

    float acc[8];
    {
        uint4 v = Abf[(size_t)node * 16 + lane];   // self term
        acc[0] = __uint_as_float(v.x << 16);
        acc[1] = __uint_as_float(v.x & 0xffff0000u);
        acc[2] = __uint_as_float(v.y << 16);
        acc[3] = __uint_as_float(v.y & 0xffff0000u);
        acc[4] = __uint_as_float(v.z << 16);
        acc[5] = __uint_as_float(v.z & 0xffff0000u);
        acc[6] = __uint_as_float(v.w << 16);
        acc[7] = __uint_as_float(v.w & 0xffff0000u);
    }
    unsigned o = off[node];
    unsigned d = cnt[node];

    unsigned e = 0;
    for (; e + 4 <= d; e += 4) {
        int s0 = csr[o + e + 0];
        int s1 = csr[o + e + 1];
        int s2 = csr[o + e + 2];
        int s3 = csr[o + e + 3];
        uint4 v0 = Abf[(size_t)s0 * 16 + lane];
        uint4 v1 = Abf[(size_t)s1 * 16 + lane];
        uint4 v2 = Abf[(size_t)s2 * 16 + lane];
        uint4 v3 = Abf[(size_t)s3 * 16 + lane];
        bf8_add(acc, v0);
        bf8_add(acc, v1);
        bf8_add(acc, v2);
        bf8_add(acc, v3);
    }
    for (; e < d; ++e) {
        int s = csr[o + e];
        uint4 v = Abf[(size_t)s * 16 + lane];
        bf8_add(acc, v);
    }

    float nm = nrm[node];
    float4 b0 = *(const float4*)(bias + lane * 8);
    float4 b1 = *(const float4*)(bias + lane * 8 + 4);
    float4 r0, r1;
    r0.x = fmaxf(acc[0] * nm + b0.x, 0.f);
    r0.y = fmaxf(acc[1] * nm + b0.y, 0.f);
    r0.z = fmaxf(acc[2] * nm + b0.z, 0.f);
    r0.w = fmaxf(acc[3] * nm + b0.w, 0.f);
    r1.x = fmaxf(acc[4] * nm + b1.x, 0.f);
    r1.y = fmaxf(acc[5] * nm + b1.y, 0.f);
    r1.z = fmaxf(acc[6] * nm + b1.z, 0.f);
    r1.w = fmaxf(acc[7] * nm + b1.w, 0.f);
    ((float4*)B)[(size_t)node * 32 + lane * 2]     = r0;
    ((float4*)B)[(size_t)node * 32 + lane * 2 + 1] = r1;
}

// ---------------- final: logits = X @ Wf + bf; out = log_softmax ------------

__global__ __launch_bounds__(256) void final_kernel(const float* __restrict__ X,
                                                    const float* __restrict__ Wf,
                                                    const float* __restrict__ bf,
                                                    float* __restrict__ out, int nrows) {
    __shared__ float xs[32][129];
    __shared__ float wf[DH * NC];
    __shared__ float ls[32][NC + 1];
    __shared__ float mrow[32], srow[32];

    const int tid = threadIdx.x;
    const int base = blockIdx.x * 32;

    for (int i = tid; i < DH * NC; i += 256) wf[i] = Wf[i];
    for (int i = tid * 4; i < 32 * DH; i += 1024) {
        int r = i >> 7, c = i & 127;
        int gr = base + r;
        float4 v = make_float4(0.f, 0.f, 0.f, 0.f);
        if (gr < nrows) v = *(const float4*)(X + (size_t)gr * DH + c);
        xs[r][c] = v.x; xs[r][c + 1] = v.y; xs[r][c + 2] = v.z; xs[r][c + 3] = v.w;
    }
    __syncthreads();

    for (int o = tid; o < 32 * NC; o += 256) {
        int r = o / NC, c = o - r * NC;
        float acc = bf[c];
#pragma unroll 8
        for (int k = 0; k < DH; ++k) acc += xs[r][k] * wf[k * NC + c];
        ls[r][c] = acc;
    }
    __syncthreads();

    if (tid < 32) {
        float m = -1e30f;
        for (int c = 0; c < NC; ++c) m = fmaxf(m, ls[tid][c]);
        float s = 0.f;
        for (int c = 0; c < NC; ++c) s += expf(ls[tid][c] - m);
        mrow[tid] = m;
        srow[tid] = logf(s);
    }
    __syncthreads();

    for (int o = tid; o < 32 * NC; o += 256) {
        int r = o / NC, c = o - r * NC;
        int gr = base + r;
        if (gr < nrows) out[(size_t)gr * NC + c] = ls[r][c] - mrow[r] - srow[r];
    }
}

// ---------------------------------------------------------------------------

extern "C" void kernel_launch(void* const* d_in, const int* in_sizes, int n_in,
                              void* d_out, int out_size, void* d_ws, size_t ws_size,
                              hipStream_t stream) {
    const float* x   = (const float*)d_in[0];
    const int*   ei  = (const int*)d_in[1];
    const float* W1  = (const float*)d_in[2];
    const float* b1  = (const float*)d_in[3];
    const float* W2  = (const float*)d_in[4];
    const float* b2  = (const float*)d_in[5];
    const float* W3  = (const float*)d_in[6];
    const float* b3  = (const float*)d_in[7];
    const float* Wp1 = (const float*)d_in[8];
    const float* bp1 = (const float*)d_in[9];
    const float* Wp2 = (const float*)d_in[10];
    const float* bp2 = (const float*)d_in[11];
    float* out = (float*)d_out;

    const int N = in_sizes[0] / DH;
    const int E = in_sizes[1] / 2;
    const int* src = ei;
    const int* dst = ei + E;

    // workspace carve (all 16B aligned)
    char* w = (char*)d_ws;
    unsigned short* A = (unsigned short*)w; w += (size_t)N * DH * 2;   // bf16 gather buf
    float*    Bf     = (float*)w;    w += (size_t)N * DH * 4;
    int*      csr    = (int*)w;      w += (size_t)E * 4;
    unsigned* cnt    = (unsigned*)w; w += (size_t)N * 4;
    unsigned* cursor = (unsigned*)w; w += 16;
    unsigned* off    = (unsigned*)w; w += (size_t)N * 4;
    unsigned* pos    = (unsigned*)w; w += (size_t)N * 4;
    float*    nrm    = (float*)w;    w += (size_t)N * 4;
    float*    Wf     = (float*)w;    w += DH * NC * 4;
    float*    bfz    = (float*)w;    w += 256;

    const int gE = (E + 255) / 256;
    const int gN = (N + 255) / 256;

    hipMemsetAsync(cnt, 0, (size_t)N * 4 + 16, stream);  // cnt + cursor
    count_deg<<<gE, 256, 0, stream>>>(dst, E, cnt);
    norm_off<<<gN, 256, 0, stream>>>(cnt, nrm, off, pos, cursor, N);
    fill_csr<<<gE, 256, 0, stream>>>(src, dst, E, pos, csr);
    fuse_w<<<(DH * NC + NC + 255) / 256, 256, 0, stream>>>(Wp1, bp1, Wp2, bp2, Wf, bfz);

    const int gG = (N + 63) / 64;
    const int gA = (N + 15) / 16;

    gemm_scale<<<gG, 256, 0, stream>>>(x,  W1, nrm, A, N);
    aggregate <<<gA, 256, 0, stream>>>((const uint4*)A, csr, off, cnt, nrm, b1, Bf, N);
    gemm_scale<<<gG, 256, 0, stream>>>(Bf, W2, nrm, A, N);
    aggregate <<<gA, 256, 0, stream>>>((const uint4*)A, csr, off, cnt, nrm, b2, Bf, N);
    gemm_scale<<<gG, 256, 0, stream>>>(Bf, W3, nrm, A, N);
    aggregate <<<gA, 256, 0, stream>>>((const uint4*)A, csr, off, cnt, nrm, b3, Bf, N);

    final_kernel<<<(N + 31) / 32, 256, 0, stream>>>(Bf, Wf, bfz, out, N);
}

// Round 3
// 587.542 us; speedup vs baseline: 1.4841x; 1.2700x over previous
//
#include <hip/hip_runtime.h>
#include <hip/hip_bf16.h>
#include <math.h>

// ---------------------------------------------------------------------------
// GCN: 3x GCNConv(128->128) + fused (Wp1@Wp2) head + log_softmax.
// Round 3: two-level LDS counting-sort CSR build. fill_csr's 106 MB of
// partial-line scattered writes (1.6M x 4B -> 64B dirty lines) replaced by
// bucket-sorted coalesced writes. count_deg/norm_off folded into bucket_csr.
//   - h_scaled = bf16((h @ W) * norm[row])  (GEMM epilogue)
//   - layer_out = relu(norm[i]*(sum_{in} h_scaled[src] + h_scaled[i]) + b)
// ---------------------------------------------------------------------------

#define DH 128    // feature dim (D == H == 128)
#define NC 40     // classes
#define BN 256    // nodes per bucket
#define MAXNB 512 // max buckets (N <= 131072)
#define CH 8192   // edges per scatter block
#define ECAP 6144 // LDS edge capacity in bucket_csr (mean ~4092, +32 sigma)

__device__ __forceinline__ unsigned short f2bf(float f) {
    unsigned u = __float_as_uint(f);
    unsigned r = (u + 0x7fffu + ((u >> 16) & 1u)) >> 16;   // RNE
    return (unsigned short)r;
}

// ---------------- bucket-level histogram (LDS, then coalesced merge) --------

__global__ __launch_bounds__(256) void bucket_hist(const int* __restrict__ dst, int E,
                                                   unsigned* __restrict__ bcnt) {
    __shared__ unsigned h[MAXNB];
    int tid = threadIdx.x;
    for (int i = tid; i < MAXNB; i += 256) h[i] = 0;
    __syncthreads();
    int e0 = blockIdx.x * CH;
    int e1 = min(e0 + CH, E);
    for (int i = e0 + tid; i < e1; i += 256)
        atomicAdd(&h[dst[i] >> 8], 1u);
    __syncthreads();
    for (int i = tid; i < MAXNB; i += 256)
        if (h[i]) atomicAdd(&bcnt[i], h[i]);
}

// disjoint range per bucket; order irrelevant
__global__ __launch_bounds__(256) void bucket_alloc(const unsigned* __restrict__ bcnt,
                                                    unsigned* __restrict__ bbase,
                                                    unsigned* __restrict__ bpos,
                                                    unsigned* __restrict__ cursor, int NB) {
    int i = blockIdx.x * 256 + threadIdx.x;
    if (i < NB) {
        unsigned c = bcnt[i];
        unsigned o = atomicAdd(cursor, c);
        bbase[i] = o;
        bpos[i] = o;
    }
}

// ---------------- scatter edges into bucket-grouped ebuf (LDS sort) ---------
// packed edge: (src << 8) | (dst & 255); src < 2^24, dst_local < 256.

__global__ __launch_bounds__(256) void bucket_scatter(const int* __restrict__ src,
                                                      const int* __restrict__ dst, int E,
                                                      unsigned* __restrict__ bpos,
                                                      unsigned* __restrict__ ebuf) {
    __shared__ unsigned hist[MAXNB];
    __shared__ unsigned lbase[MAXNB];   // local base within chunk
    __shared__ unsigned gbase[MAXNB];   // global base of this block's segment
    __shared__ unsigned cur[MAXNB];
    __shared__ unsigned sorted[CH];
    __shared__ unsigned short sbkt[CH];
    __shared__ unsigned total;

    int tid = threadIdx.x;
    int e0 = blockIdx.x * CH;
    int nE = min(CH, E - e0);

    for (int i = tid; i < MAXNB; i += 256) { hist[i] = 0; cur[i] = 0; }
    if (tid == 0) total = 0;
    __syncthreads();

    for (int i = tid; i < nE; i += 256)
        atomicAdd(&hist[dst[e0 + i] >> 8], 1u);
    __syncthreads();

    for (int i = tid; i < MAXNB; i += 256) {
        unsigned h = hist[i];
        lbase[i] = h ? atomicAdd(&total, h) : 0u;           // local disjoint ranges
        gbase[i] = h ? atomicAdd(&bpos[i], h) : 0u;         // global disjoint ranges
    }
    __syncthreads();

    for (int i = tid; i < nE; i += 256) {
        int s = src[e0 + i];
        int d = dst[e0 + i];
        unsigned b = (unsigned)d >> 8;
        unsigned r = atomicAdd(&cur[b], 1u);
        unsigned p = lbase[b] + r;
        sorted[p] = ((unsigned)s << 8) | ((unsigned)d & 255u);
        sbkt[p] = (unsigned short)b;
    }
    __syncthreads();

    // coalesced copy-out: consecutive p within a bucket run -> consecutive global
    for (int p = tid; p < nE; p += 256) {
        unsigned b = sbkt[p];
        ebuf[gbase[b] + (p - lbase[b])] = sorted[p];
    }
}

// ---------------- per-bucket node-level counting sort -> csr/off/cnt/nrm ----

__global__ __launch_bounds__(256) void bucket_csr(const unsigned* __restrict__ ebuf,
                                                  const unsigned* __restrict__ bbase,
                                                  const unsigned* __restrict__ bcnt,
                                                  unsigned* __restrict__ off,
                                                  unsigned* __restrict__ cnt,
                                                  float* __restrict__ nrm,
                                                  int* __restrict__ csr, int N) {
    __shared__ unsigned h[BN];
    __shared__ unsigned nb[BN];
    __shared__ unsigned ncur[BN];
    __shared__ int lcsr[ECAP];
    __shared__ unsigned tot;

    int b = blockIdx.x;
    int tid = threadIdx.x;
    unsigned ebase = bbase[b];
    unsigned ecnt = bcnt[b];

    h[tid] = 0;
    if (tid == 0) tot = 0;
    __syncthreads();

    for (unsigned i = tid; i < ecnt; i += 256)
        atomicAdd(&h[ebuf[ebase + i] & 255u], 1u);
    __syncthreads();

    unsigned myh = h[tid];
    unsigned mybase = myh ? atomicAdd(&tot, myh) : 0u;      // disjoint node ranges
    nb[tid] = mybase;
    ncur[tid] = 0;
    int node = b * BN + tid;
    if (node < N) {
        off[node] = ebase + mybase;
        cnt[node] = myh;
        nrm[node] = rsqrtf((float)myh + 1.0f);
    }
    __syncthreads();

    if (ecnt <= ECAP) {
        for (unsigned i = tid; i < ecnt; i += 256) {
            unsigned v = ebuf[ebase + i];
            unsigned nl = v & 255u;
            unsigned r = atomicAdd(&ncur[nl], 1u);
            lcsr[nb[nl] + r] = (int)(v >> 8);
        }
        __syncthreads();
        for (unsigned i = tid; i < ecnt; i += 256)
            csr[ebase + i] = lcsr[i];
    } else {
        // fallback (statistically unreachable): direct global scatter
        for (unsigned i = tid; i < ecnt; i += 256) {
            unsigned v = ebuf[ebase + i];
            unsigned nl = v & 255u;
            unsigned r = atomicAdd(&ncur[nl], 1u);
            csr[ebase + nb[nl] + r] = (int)(v >> 8);
        }
    }
}

// ---------------- head weight fusion: Wf = Wp1@Wp2, bf = bp1@Wp2 + bp2 ------

__global__ __launch_bounds__(256) void fuse_w(const float* __restrict__ Wp1,
                                              const float* __restrict__ bp1,
                                              const float* __restrict__ Wp2,
                                              const float* __restrict__ bp2,
                                              float* __restrict__ Wf,
                                              float* __restrict__ bf) {
    int o = blockIdx.x * 256 + threadIdx.x;
    if (o < DH * NC) {
        int k = o / NC, c = o - k * NC;
        float acc = 0.f;
        for (int j = 0; j < DH; ++j) acc += Wp1[k * DH + j] * Wp2[j * NC + c];
        Wf[o] = acc;
    } else if (o < DH * NC + NC) {
        int c = o - DH * NC;
        float acc = bp2[c];
        for (int j = 0; j < DH; ++j) acc += bp1[j] * Wp2[j * NC + c];
        bf[c] = acc;
    }
}

// ---------------- GEMM (NxDH @ DHxDH), epilogue: *norm[row] -> bf16 ---------

__global__ __launch_bounds__(256) void gemm_scale(const float* __restrict__ X,
                                                  const float* __restrict__ W,
                                                  const float* __restrict__ nrm,
                                                  unsigned short* __restrict__ outb,
                                                  int nrows) {
    __shared__ float xs[64][36];
    __shared__ float ws[32][128];

    const int tid = threadIdx.x;
    const int tx = tid & 15;
    const int ty = tid >> 4;
    const int rbase = blockIdx.x * 64;

    float acc[4][8];
#pragma unroll
    for (int i = 0; i < 4; ++i)
#pragma unroll
        for (int j = 0; j < 8; ++j) acc[i][j] = 0.f;

    const int lrow = tid >> 2;
    const int lcol = (tid & 3) * 8;

    for (int kk = 0; kk < DH; kk += 32) {
        {
            float4 v0 = make_float4(0.f, 0.f, 0.f, 0.f), v1 = v0;
            int gr = rbase + lrow;
            if (gr < nrows) {
                const float* p = X + (size_t)gr * DH + kk + lcol;
                v0 = *(const float4*)p;
                v1 = *(const float4*)(p + 4);
            }
            *(float4*)&xs[lrow][lcol]     = v0;
            *(float4*)&xs[lrow][lcol + 4] = v1;
        }
        {
            int krow = tid >> 3;
            int c    = (tid & 7) * 16;
            const float* p = W + (size_t)(kk + krow) * DH + c;
            *(float4*)&ws[krow][c]      = *(const float4*)(p);
            *(float4*)&ws[krow][c + 4]  = *(const float4*)(p + 4);
            *(float4*)&ws[krow][c + 8]  = *(const float4*)(p + 8);
            *(float4*)&ws[krow][c + 12] = *(const float4*)(p + 12);
        }
        __syncthreads();

#pragma unroll
        for (int k = 0; k < 32; ++k) {
            float a0 = xs[ty * 4 + 0][k];
            float a1 = xs[ty * 4 + 1][k];
            float a2 = xs[ty * 4 + 2][k];
            float a3 = xs[ty * 4 + 3][k];
            float4 w0 = *(float4*)&ws[k][tx * 4];
            float4 w1 = *(float4*)&ws[k][64 + tx * 4];
            acc[0][0] += a0 * w0.x; acc[0][1] += a0 * w0.y; acc[0][2] += a0 * w0.z; acc[0][3] += a0 * w0.w;
            acc[0][4] += a0 * w1.x; acc[0][5] += a0 * w1.y; acc[0][6] += a0 * w1.z; acc[0][7] += a0 * w1.w;
            acc[1][0] += a1 * w0.x; acc[1][1] += a1 * w0.y; acc[1][2] += a1 * w0.z; acc[1][3] += a1 * w0.w;
            acc[1][4] += a1 * w1.x; acc[1][5] += a1 * w1.y; acc[1][6] += a1 * w1.z; acc[1][7] += a1 * w1.w;
            acc[2][0] += a2 * w0.x; acc[2][1] += a2 * w0.y; acc[2][2] += a2 * w0.z; acc[2][3] += a2 * w0.w;
            acc[2][4] += a2 * w1.x; acc[2][5] += a2 * w1.y; acc[2][6] += a2 * w1.z; acc[2][7] += a2 * w1.w;
            acc[3][0] += a3 * w0.x; acc[3][1] += a3 * w0.y; acc[3][2] += a3 * w0.z; acc[3][3] += a3 * w0.w;
            acc[3][4] += a3 * w1.x; acc[3][5] += a3 * w1.y; acc[3][6] += a3 * w1.z; acc[3][7] += a3 * w1.w;
        }
        __syncthreads();
    }

#pragma unroll
    for (int i = 0; i < 4; ++i) {
        int r = rbase + ty * 4 + i;
        if (r < nrows) {
            float s = nrm[r];
            ushort4 o0, o1;
            o0.x = f2bf(acc[i][0] * s); o0.y = f2bf(acc[i][1] * s);
            o0.z = f2bf(acc[i][2] * s); o0.w = f2bf(acc[i][3] * s);
            o1.x = f2bf(acc[i][4] * s); o1.y = f2bf(acc[i][5] * s);
            o1.z = f2bf(acc[i][6] * s); o1.w = f2bf(acc[i][7] * s);
            *(ushort4*)(outb + (size_t)r * DH + tx * 4)      = o0;
            *(ushort4*)(outb + (size_t)r * DH + 64 + tx * 4) = o1;
        }
    }
}

// ---------------- CSR aggregation: B = relu(norm*(sum Abf[src] + Abf[i]) + b)

__device__ __forceinline__ void bf8_add(float* acc, uint4 v) {
    acc[0] += __uint_as_float(v.x << 16);
    acc[1] += __uint_as_float(v.x & 0xffff0000u);
    acc[2] += __uint_as_float(v.y << 16);
    acc[3] += __uint_as_float(v.y & 0xffff0000u);
    acc[4] += __uint_as_float(v.z << 16);
    acc[5] += __uint_as_float(v.z & 0xffff0000u);
    acc[6] += __uint_as_float(v.w << 16);
    acc[7] += __uint_as_float(v.w & 0xffff0000u);
}

__global__ __launch_bounds__(256) void aggregate(const uint4* __restrict__ Abf,
                                                 const int* __restrict__ csr,
                                                 const unsigned* __restrict__ off,
                                                 const unsigned* __restrict__ cnt,
                                                 const float* __restrict__ nrm,
                                                 const float* __restrict__ bias,
                                                 float* __restrict__ B, int N) {
    int node = blockIdx.x * 16 + (threadIdx.x >> 4);
    int lane = threadIdx.x & 15;
    if (node >= N) return;

    float acc[8];
    {
        uint4 v = Abf[(size_t)node * 16 + lane];   // self term
        acc[0] = __uint_as_float(v.x << 16);
        acc[1] = __uint_as_float(v.x & 0xffff0000u);
        acc[2] = __uint_as_float(v.y << 16);
        acc[3] = __uint_as_float(v.y & 0xffff0000u);
        acc[4] = __uint_as_float(v.z << 16);
        acc[5] = __uint_as_float(v.z & 0xffff0000u);
        acc[6] = __uint_as_float(v.w << 16);
        acc[7] = __uint_as_float(v.w & 0xffff0000u);
    }
    unsigned o = off[node];
    unsigned d = cnt[node];

    unsigned e = 0;
    for (; e + 4 <= d; e += 4) {
        int s0 = csr[o + e + 0];
        int s1 = csr[o + e + 1];
        int s2 = csr[o + e + 2];
        int s3 = csr[o + e + 3];
        uint4 v0 = Abf[(size_t)s0 * 16 + lane];
        uint4 v1 = Abf[(size_t)s1 * 16 + lane];
        uint4 v2 = Abf[(size_t)s2 * 16 + lane];
        uint4 v3 = Abf[(size_t)s3 * 16 + lane];
        bf8_add(acc, v0);
        bf8_add(acc, v1);
        bf8_add(acc, v2);
        bf8_add(acc, v3);
    }
    for (; e < d; ++e) {
        int s = csr[o + e];
        uint4 v = Abf[(size_t)s * 16 + lane];
        bf8_add(acc, v);
    }

    float nm = nrm[node];
    float4 b0 = *(const float4*)(bias + lane * 8);
    float4 b1 = *(const float4*)(bias + lane * 8 + 4);
    float4 r0, r1;
    r0.x = fmaxf(acc[0] * nm + b0.x, 0.f);
    r0.y = fmaxf(acc[1] * nm + b0.y, 0.f);
    r0.z = fmaxf(acc[2] * nm + b0.z, 0.f);
    r0.w = fmaxf(acc[3] * nm + b0.w, 0.f);
    r1.x = fmaxf(acc[4] * nm + b1.x, 0.f);
    r1.y = fmaxf(acc[5] * nm + b1.y, 0.f);
    r1.z = fmaxf(acc[6] * nm + b1.z, 0.f);
    r1.w = fmaxf(acc[7] * nm + b1.w, 0.f);
    ((float4*)B)[(size_t)node * 32 + lane * 2]     = r0;
    ((float4*)B)[(size_t)node * 32 + lane * 2 + 1] = r1;
}

// ---------------- final: logits = X @ Wf + bf; out = log_softmax ------------

__global__ __launch_bounds__(256) void final_kernel(const float* __restrict__ X,
                                                    const float* __restrict__ Wf,
                                                    const float* __restrict__ bf,
                                                    float* __restrict__ out, int nrows) {
    __shared__ float xs[32][129];
    __shared__ float wf[DH * NC];
    __shared__ float ls[32][NC + 1];
    __shared__ float mrow[32], srow[32];

    const int tid = threadIdx.x;
    const int base = blockIdx.x * 32;

    for (int i = tid; i < DH * NC; i += 256) wf[i] = Wf[i];
    for (int i = tid * 4; i < 32 * DH; i += 1024) {
        int r = i >> 7, c = i & 127;
        int gr = base + r;
        float4 v = make_float4(0.f, 0.f, 0.f, 0.f);
        if (gr < nrows) v = *(const float4*)(X + (size_t)gr * DH + c);
        xs[r][c] = v.x; xs[r][c + 1] = v.y; xs[r][c + 2] = v.z; xs[r][c + 3] = v.w;
    }
    __syncthreads();

    for (int o = tid; o < 32 * NC; o += 256) {
        int r = o / NC, c = o - r * NC;
        float acc = bf[c];
#pragma unroll 8
        for (int k = 0; k < DH; ++k) acc += xs[r][k] * wf[k * NC + c];
        ls[r][c] = acc;
    }
    __syncthreads();

    if (tid < 32) {
        float m = -1e30f;
        for (int c = 0; c < NC; ++c) m = fmaxf(m, ls[tid][c]);
        float s = 0.f;
        for (int c = 0; c < NC; ++c) s += expf(ls[tid][c] - m);
        mrow[tid] = m;
        srow[tid] = logf(s);
    }
    __syncthreads();

    for (int o = tid; o < 32 * NC; o += 256) {
        int r = o / NC, c = o - r * NC;
        int gr = base + r;
        if (gr < nrows) out[(size_t)gr * NC + c] = ls[r][c] - mrow[r] - srow[r];
    }
}

// ---------------------------------------------------------------------------

extern "C" void kernel_launch(void* const* d_in, const int* in_sizes, int n_in,
                              void* d_out, int out_size, void* d_ws, size_t ws_size,
                              hipStream_t stream) {
    const float* x   = (const float*)d_in[0];
    const int*   ei  = (const int*)d_in[1];
    const float* W1  = (const float*)d_in[2];
    const float* b1  = (const float*)d_in[3];
    const float* W2  = (const float*)d_in[4];
    const float* b2  = (const float*)d_in[5];
    const float* W3  = (const float*)d_in[6];
    const float* b3  = (const float*)d_in[7];
    const float* Wp1 = (const float*)d_in[8];
    const float* bp1 = (const float*)d_in[9];
    const float* Wp2 = (const float*)d_in[10];
    const float* bp2 = (const float*)d_in[11];
    float* out = (float*)d_out;

    const int N = in_sizes[0] / DH;
    const int E = in_sizes[1] / 2;
    const int* src = ei;
    const int* dst = ei + E;
    const int NB = (N + BN - 1) / BN;

    // workspace carve (all 16B aligned)
    char* w = (char*)d_ws;
    unsigned short* A = (unsigned short*)w; w += (size_t)N * DH * 2;   // bf16 gather buf
    float*    Bf     = (float*)w;    w += (size_t)N * DH * 4;
    int*      csr    = (int*)w;      w += (size_t)E * 4;
    unsigned* ebuf   = (unsigned*)w; w += (size_t)E * 4;
    unsigned* bcnt   = (unsigned*)w; w += MAXNB * 4;
    unsigned* cursor = (unsigned*)w; w += 16;
    unsigned* bbase  = (unsigned*)w; w += MAXNB * 4;
    unsigned* bpos   = (unsigned*)w; w += MAXNB * 4;
    unsigned* off    = (unsigned*)w; w += (size_t)N * 4;
    unsigned* cnt    = (unsigned*)w; w += (size_t)N * 4;
    float*    nrm    = (float*)w;    w += (size_t)N * 4;
    float*    Wf     = (float*)w;    w += DH * NC * 4;
    float*    bfz    = (float*)w;    w += 256;

    const int gC = (E + CH - 1) / CH;

    hipMemsetAsync(bcnt, 0, MAXNB * 4 + 16, stream);   // bcnt + cursor
    bucket_hist   <<<gC, 256, 0, stream>>>(dst, E, bcnt);
    bucket_alloc  <<<(NB + 255) / 256, 256, 0, stream>>>(bcnt, bbase, bpos, cursor, NB);
    bucket_scatter<<<gC, 256, 0, stream>>>(src, dst, E, bpos, ebuf);
    bucket_csr    <<<NB, 256, 0, stream>>>(ebuf, bbase, bcnt, off, cnt, nrm, csr, N);
    fuse_w<<<(DH * NC + NC + 255) / 256, 256, 0, stream>>>(Wp1, bp1, Wp2, bp2, Wf, bfz);

    const int gG = (N + 63) / 64;
    const int gA = (N + 15) / 16;

    gemm_scale<<<gG, 256, 0, stream>>>(x,  W1, nrm, A, N);
    aggregate <<<gA, 256, 0, stream>>>((const uint4*)A, csr, off, cnt, nrm, b1, Bf, N);
    gemm_scale<<<gG, 256, 0, stream>>>(Bf, W2, nrm, A, N);
    aggregate <<<gA, 256, 0, stream>>>((const uint4*)A, csr, off, cnt, nrm, b2, Bf, N);
    gemm_scale<<<gG, 256, 0, stream>>>(Bf, W3, nrm, A, N);
    aggregate <<<gA, 256, 0, stream>>>((const uint4*)A, csr, off, cnt, nrm, b3, Bf, N);

    final_kernel<<<(N + 31) / 32, 256, 0, stream>>>(Bf, Wf, bfz, out, N);
}

// Round 4
// 461.264 us; speedup vs baseline: 1.8904x; 1.2738x over previous
//
#include <hip/hip_runtime.h>
#include <hip/hip_bf16.h>
#include <math.h>

// ---------------------------------------------------------------------------
// GCN: 3x GCNConv(128->128) + fused (Wp1@Wp2) head + log_softmax.
// Round 4: MFMA bf16 GEMMs (no LDS; A-frags streamed from global, B-frags
// from pre-transposed bf16 weights), MFMA head + shfl log_softmax, bf16
// activations end-to-end (fp32 accumulate everywhere).
// ---------------------------------------------------------------------------

#define DH 128    // feature dim (D == H == 128)
#define NC 40     // classes
#define BN 256    // nodes per bucket
#define MAXNB 512 // max buckets (N <= 131072)
#define CH 8192   // edges per scatter block
#define ECAP 6144 // LDS edge capacity in bucket_csr

typedef __attribute__((ext_vector_type(8))) short bf16x8;
typedef __attribute__((ext_vector_type(4))) float f32x4;

__device__ __forceinline__ unsigned short f2bf(float f) {
    unsigned u = __float_as_uint(f);
    unsigned r = (u + 0x7fffu + ((u >> 16) & 1u)) >> 16;   // RNE
    return (unsigned short)r;
}
__device__ __forceinline__ unsigned pack2(float lo, float hi) {
    return (unsigned)f2bf(lo) | ((unsigned)f2bf(hi) << 16);
}

// ---------------- bucket-level histogram (LDS, then coalesced merge) --------

__global__ __launch_bounds__(256) void bucket_hist(const int* __restrict__ dst, int E,
                                                   unsigned* __restrict__ bcnt) {
    __shared__ unsigned h[MAXNB];
    int tid = threadIdx.x;
    for (int i = tid; i < MAXNB; i += 256) h[i] = 0;
    __syncthreads();
    int e0 = blockIdx.x * CH;
    int e1 = min(e0 + CH, E);
    for (int i = e0 + tid; i < e1; i += 256)
        atomicAdd(&h[dst[i] >> 8], 1u);
    __syncthreads();
    for (int i = tid; i < MAXNB; i += 256)
        if (h[i]) atomicAdd(&bcnt[i], h[i]);
}

__global__ __launch_bounds__(256) void bucket_alloc(const unsigned* __restrict__ bcnt,
                                                    unsigned* __restrict__ bbase,
                                                    unsigned* __restrict__ bpos,
                                                    unsigned* __restrict__ cursor, int NB) {
    int i = blockIdx.x * 256 + threadIdx.x;
    if (i < NB) {
        unsigned c = bcnt[i];
        unsigned o = atomicAdd(cursor, c);
        bbase[i] = o;
        bpos[i] = o;
    }
}

__global__ __launch_bounds__(256) void bucket_scatter(const int* __restrict__ src,
                                                      const int* __restrict__ dst, int E,
                                                      unsigned* __restrict__ bpos,
                                                      unsigned* __restrict__ ebuf) {
    __shared__ unsigned hist[MAXNB];
    __shared__ unsigned lbase[MAXNB];
    __shared__ unsigned gbase[MAXNB];
    __shared__ unsigned cur[MAXNB];
    __shared__ unsigned sorted[CH];
    __shared__ unsigned short sbkt[CH];
    __shared__ unsigned total;

    int tid = threadIdx.x;
    int e0 = blockIdx.x * CH;
    int nE = min(CH, E - e0);

    for (int i = tid; i < MAXNB; i += 256) { hist[i] = 0; cur[i] = 0; }
    if (tid == 0) total = 0;
    __syncthreads();

    for (int i = tid; i < nE; i += 256)
        atomicAdd(&hist[dst[e0 + i] >> 8], 1u);
    __syncthreads();

    for (int i = tid; i < MAXNB; i += 256) {
        unsigned h = hist[i];
        lbase[i] = h ? atomicAdd(&total, h) : 0u;
        gbase[i] = h ? atomicAdd(&bpos[i], h) : 0u;
    }
    __syncthreads();

    for (int i = tid; i < nE; i += 256) {
        int s = src[e0 + i];
        int d = dst[e0 + i];
        unsigned b = (unsigned)d >> 8;
        unsigned r = atomicAdd(&cur[b], 1u);
        unsigned p = lbase[b] + r;
        sorted[p] = ((unsigned)s << 8) | ((unsigned)d & 255u);
        sbkt[p] = (unsigned short)b;
    }
    __syncthreads();

    for (int p = tid; p < nE; p += 256) {
        unsigned b = sbkt[p];
        ebuf[gbase[b] + (p - lbase[b])] = sorted[p];
    }
}

__global__ __launch_bounds__(256) void bucket_csr(const unsigned* __restrict__ ebuf,
                                                  const unsigned* __restrict__ bbase,
                                                  const unsigned* __restrict__ bcnt,
                                                  unsigned* __restrict__ off,
                                                  unsigned* __restrict__ cnt,
                                                  float* __restrict__ nrm,
                                                  int* __restrict__ csr, int N) {
    __shared__ unsigned h[BN];
    __shared__ unsigned nb[BN];
    __shared__ unsigned ncur[BN];
    __shared__ int lcsr[ECAP];
    __shared__ unsigned tot;

    int b = blockIdx.x;
    int tid = threadIdx.x;
    unsigned ebase = bbase[b];
    unsigned ecnt = bcnt[b];

    h[tid] = 0;
    if (tid == 0) tot = 0;
    __syncthreads();

    for (unsigned i = tid; i < ecnt; i += 256)
        atomicAdd(&h[ebuf[ebase + i] & 255u], 1u);
    __syncthreads();

    unsigned myh = h[tid];
    unsigned mybase = myh ? atomicAdd(&tot, myh) : 0u;
    nb[tid] = mybase;
    ncur[tid] = 0;
    int node = b * BN + tid;
    if (node < N) {
        off[node] = ebase + mybase;
        cnt[node] = myh;
        nrm[node] = rsqrtf((float)myh + 1.0f);
    }
    __syncthreads();

    if (ecnt <= ECAP) {
        for (unsigned i = tid; i < ecnt; i += 256) {
            unsigned v = ebuf[ebase + i];
            unsigned nl = v & 255u;
            unsigned r = atomicAdd(&ncur[nl], 1u);
            lcsr[nb[nl] + r] = (int)(v >> 8);
        }
        __syncthreads();
        for (unsigned i = tid; i < ecnt; i += 256)
            csr[ebase + i] = lcsr[i];
    } else {
        for (unsigned i = tid; i < ecnt; i += 256) {
            unsigned v = ebuf[ebase + i];
            unsigned nl = v & 255u;
            unsigned r = atomicAdd(&ncur[nl], 1u);
            csr[ebase + nb[nl] + r] = (int)(v >> 8);
        }
    }
}

// ---------------- casts: x -> bf16, W -> transposed bf16 --------------------

__global__ __launch_bounds__(256) void cast_x(const float* __restrict__ x,
                                              unsigned short* __restrict__ xb, int n4) {
    int i = blockIdx.x * 256 + threadIdx.x;
    if (i < n4) {
        float4 v = ((const float4*)x)[i];
        ushort4 o;
        o.x = f2bf(v.x); o.y = f2bf(v.y); o.z = f2bf(v.z); o.w = f2bf(v.w);
        ((ushort4*)xb)[i] = o;
    }
}

// Wt[l][n][k] = W_l[k][n], bf16
__global__ __launch_bounds__(256) void cast_w(const float* __restrict__ W1,
                                              const float* __restrict__ W2,
                                              const float* __restrict__ W3,
                                              unsigned short* __restrict__ Wt) {
    int id = blockIdx.x * 256 + threadIdx.x;
    if (id < 3 * DH * DH) {
        int l = id >> 14, r = id & (DH * DH - 1);
        int k = r >> 7, n = r & 127;
        const float* W = (l == 0) ? W1 : (l == 1) ? W2 : W3;
        Wt[l * DH * DH + n * DH + k] = f2bf(W[k * DH + n]);
    }
}

// head: Wft[c][k] = (Wp1@Wp2)[k][c] bf16 (c padded to 48), bfh[c] = bp1@Wp2+bp2
__global__ __launch_bounds__(256) void fuse_w(const float* __restrict__ Wp1,
                                              const float* __restrict__ bp1,
                                              const float* __restrict__ Wp2,
                                              const float* __restrict__ bp2,
                                              unsigned short* __restrict__ Wft,
                                              float* __restrict__ bfh) {
    int o = blockIdx.x * 256 + threadIdx.x;
    if (o < 48 * DH) {
        int c = o >> 7, k = o & 127;
        float acc = 0.f;
        if (c < NC)
            for (int j = 0; j < DH; ++j) acc += Wp1[k * DH + j] * Wp2[j * NC + c];
        Wft[c * DH + k] = f2bf(acc);
    } else if (o < 48 * DH + 48) {
        int c = o - 48 * DH;
        float acc = 0.f;
        if (c < NC) {
            acc = bp2[c];
            for (int j = 0; j < DH; ++j) acc += bp1[j] * Wp2[j * NC + c];
        }
        bfh[c] = acc;
    }
}

// ---------------- MFMA GEMM: out_bf16[r][:] = bf16(nrm[r] * (Xb @ W)) -------
// 16x16x32 bf16 MFMA. A[m=lane&15][k=quad*8+j]; B[k][n]: n=lane&15 (from
// Wt[n][k], contiguous); C/D: col=lane&15, row=quad*4+reg. Block=128 rows,
// wave=32 rows x 128 cols (2x8 tiles). No LDS.

__global__ __launch_bounds__(256) void gemm_mfma(const unsigned short* __restrict__ Xb,
                                                 const unsigned short* __restrict__ Wt,
                                                 const float* __restrict__ nrm,
                                                 unsigned short* __restrict__ outb,
                                                 int nrows) {
    const int tid = threadIdx.x;
    const int wave = tid >> 6;
    const int lane = tid & 63;
    const int m = lane & 15;
    const int quad = lane >> 4;
    const int rbase = blockIdx.x * 128 + wave * 32;

    f32x4 acc[2][8];
#pragma unroll
    for (int rt = 0; rt < 2; ++rt)
#pragma unroll
        for (int ct = 0; ct < 8; ++ct) acc[rt][ct] = (f32x4){0.f, 0.f, 0.f, 0.f};

#pragma unroll
    for (int kt = 0; kt < 4; ++kt) {
        const int kof = kt * 32 + quad * 8;
        bf16x8 a[2], b[8];
#pragma unroll
        for (int rt = 0; rt < 2; ++rt) {
            int r = rbase + rt * 16 + m;
            r = (r < nrows) ? r : (nrows - 1);
            a[rt] = *(const bf16x8*)(Xb + (size_t)r * DH + kof);
        }
#pragma unroll
        for (int ct = 0; ct < 8; ++ct)
            b[ct] = *(const bf16x8*)(Wt + (ct * 16 + m) * DH + kof);
#pragma unroll
        for (int rt = 0; rt < 2; ++rt)
#pragma unroll
            for (int ct = 0; ct < 8; ++ct)
                acc[rt][ct] = __builtin_amdgcn_mfma_f32_16x16x32_bf16(a[rt], b[ct], acc[rt][ct], 0, 0, 0);
    }

#pragma unroll
    for (int rt = 0; rt < 2; ++rt)
#pragma unroll
        for (int reg = 0; reg < 4; ++reg) {
            int r = rbase + rt * 16 + quad * 4 + reg;
            if (r < nrows) {
                float s = nrm[r];
#pragma unroll
                for (int ct = 0; ct < 8; ++ct)
                    outb[(size_t)r * DH + ct * 16 + m] = f2bf(acc[rt][ct][reg] * s);
            }
        }
}

// ---------------- CSR aggregation: Bb = bf16(relu(norm*(sum+self) + bias)) --
// 16 lanes per node, 16B (8 bf16) per lane.

__device__ __forceinline__ void bf8_add(float* acc, uint4 v) {
    acc[0] += __uint_as_float(v.x << 16);
    acc[1] += __uint_as_float(v.x & 0xffff0000u);
    acc[2] += __uint_as_float(v.y << 16);
    acc[3] += __uint_as_float(v.y & 0xffff0000u);
    acc[4] += __uint_as_float(v.z << 16);
    acc[5] += __uint_as_float(v.z & 0xffff0000u);
    acc[6] += __uint_as_float(v.w << 16);
    acc[7] += __uint_as_float(v.w & 0xffff0000u);
}

__global__ __launch_bounds__(256) void aggregate(const uint4* __restrict__ Abf,
                                                 const int* __restrict__ csr,
                                                 const unsigned* __restrict__ off,
                                                 const unsigned* __restrict__ cnt,
                                                 const float* __restrict__ nrm,
                                                 const float* __restrict__ bias,
                                                 unsigned short* __restrict__ Bb, int N) {
    int node = blockIdx.x * 16 + (threadIdx.x >> 4);
    int lane = threadIdx.x & 15;
    if (node >= N) return;

    float acc[8];
    {
        uint4 v = Abf[(size_t)node * 16 + lane];   // self term
        acc[0] = __uint_as_float(v.x << 16);
        acc[1] = __uint_as_float(v.x & 0xffff0000u);
        acc[2] = __uint_as_float(v.y << 16);
        acc[3] = __uint_as_float(v.y & 0xffff0000u);
        acc[4] = __uint_as_float(v.z << 16);
        acc[5] = __uint_as_float(v.z & 0xffff0000u);
        acc[6] = __uint_as_float(v.w << 16);
        acc[7] = __uint_as_float(v.w & 0xffff0000u);
    }
    unsigned o = off[node];
    unsigned d = cnt[node];

    unsigned e = 0;
    for (; e + 4 <= d; e += 4) {
        int s0 = csr[o + e + 0];
        int s1 = csr[o + e + 1];
        int s2 = csr[o + e + 2];
        int s3 = csr[o + e + 3];
        uint4 v0 = Abf[(size_t)s0 * 16 + lane];
        uint4 v1 = Abf[(size_t)s1 * 16 + lane];
        uint4 v2 = Abf[(size_t)s2 * 16 + lane];
        uint4 v3 = Abf[(size_t)s3 * 16 + lane];
        bf8_add(acc, v0);
        bf8_add(acc, v1);
        bf8_add(acc, v2);
        bf8_add(acc, v3);
    }
    for (; e < d; ++e) {
        int s = csr[o + e];
        uint4 v = Abf[(size_t)s * 16 + lane];
        bf8_add(acc, v);
    }

    float nm = nrm[node];
    float4 b0 = *(const float4*)(bias + lane * 8);
    float4 b1 = *(const float4*)(bias + lane * 8 + 4);
    float r0 = fmaxf(acc[0] * nm + b0.x, 0.f);
    float r1 = fmaxf(acc[1] * nm + b0.y, 0.f);
    float r2 = fmaxf(acc[2] * nm + b0.z, 0.f);
    float r3 = fmaxf(acc[3] * nm + b0.w, 0.f);
    float r4 = fmaxf(acc[4] * nm + b1.x, 0.f);
    float r5 = fmaxf(acc[5] * nm + b1.y, 0.f);
    float r6 = fmaxf(acc[6] * nm + b1.z, 0.f);
    float r7 = fmaxf(acc[7] * nm + b1.w, 0.f);
    uint4 ov;
    ov.x = pack2(r0, r1);
    ov.y = pack2(r2, r3);
    ov.z = pack2(r4, r5);
    ov.w = pack2(r6, r7);
    ((uint4*)Bb)[(size_t)node * 16 + lane] = ov;
}

// ---------------- MFMA head + log_softmax -----------------------------------
// logits (N x 40, padded 48 = 3 col-tiles). Wave = 16 rows. Softmax reduced
// across the 16 lanes of each quad via shfl_xor.

__global__ __launch_bounds__(256) void final_mfma(const unsigned short* __restrict__ Xb,
                                                  const unsigned short* __restrict__ Wft,
                                                  const float* __restrict__ bfh,
                                                  float* __restrict__ out, int nrows) {
    const int tid = threadIdx.x;
    const int wave = tid >> 6;
    const int lane = tid & 63;
    const int m = lane & 15;
    const int quad = lane >> 4;
    const int rbase = blockIdx.x * 64 + wave * 16;

    f32x4 acc[3];
#pragma unroll
    for (int ct = 0; ct < 3; ++ct) acc[ct] = (f32x4){0.f, 0.f, 0.f, 0.f};

#pragma unroll
    for (int kt = 0; kt < 4; ++kt) {
        const int kof = kt * 32 + quad * 8;
        int r = rbase + m;
        r = (r < nrows) ? r : (nrows - 1);
        bf16x8 a = *(const bf16x8*)(Xb + (size_t)r * DH + kof);
#pragma unroll
        for (int ct = 0; ct < 3; ++ct) {
            bf16x8 b = *(const bf16x8*)(Wft + (ct * 16 + m) * DH + kof);
            acc[ct] = __builtin_amdgcn_mfma_f32_16x16x32_bf16(a, b, acc[ct], 0, 0, 0);
        }
    }

    float bias0 = bfh[m];
    float bias1 = bfh[16 + m];
    float bias2 = bfh[32 + m];

#pragma unroll
    for (int reg = 0; reg < 4; ++reg) {
        float v0 = acc[0][reg] + bias0;
        float v1 = acc[1][reg] + bias1;
        float v2 = (m < 8) ? (acc[2][reg] + bias2) : -1e30f;
        float mx = fmaxf(fmaxf(v0, v1), v2);
#pragma unroll
        for (int dlt = 1; dlt < 16; dlt <<= 1) mx = fmaxf(mx, __shfl_xor(mx, dlt));
        float s = __expf(v0 - mx) + __expf(v1 - mx) + ((m < 8) ? __expf(v2 - mx) : 0.f);
#pragma unroll
        for (int dlt = 1; dlt < 16; dlt <<= 1) s += __shfl_xor(s, dlt);
        float ls = mx + __logf(s);
        int r = rbase + quad * 4 + reg;
        if (r < nrows) {
            out[(size_t)r * NC + m] = v0 - ls;
            out[(size_t)r * NC + 16 + m] = v1 - ls;
            if (m < 8) out[(size_t)r * NC + 32 + m] = v2 - ls;
        }
    }
}

// ---------------------------------------------------------------------------

extern "C" void kernel_launch(void* const* d_in, const int* in_sizes, int n_in,
                              void* d_out, int out_size, void* d_ws, size_t ws_size,
                              hipStream_t stream) {
    const float* x   = (const float*)d_in[0];
    const int*   ei  = (const int*)d_in[1];
    const float* W1  = (const float*)d_in[2];
    const float* b1  = (const float*)d_in[3];
    const float* W2  = (const float*)d_in[4];
    const float* b2  = (const float*)d_in[5];
    const float* W3  = (const float*)d_in[6];
    const float* b3  = (const float*)d_in[7];
    const float* Wp1 = (const float*)d_in[8];
    const float* bp1 = (const float*)d_in[9];
    const float* Wp2 = (const float*)d_in[10];
    const float* bp2 = (const float*)d_in[11];
    float* out = (float*)d_out;

    const int N = in_sizes[0] / DH;
    const int E = in_sizes[1] / 2;
    const int* src = ei;
    const int* dst = ei + E;
    const int NB = (N + BN - 1) / BN;

    // workspace carve (all 16B aligned)
    char* w = (char*)d_ws;
    unsigned short* xb  = (unsigned short*)w; w += (size_t)N * DH * 2;
    unsigned short* Ab  = (unsigned short*)w; w += (size_t)N * DH * 2;
    unsigned short* Bb  = (unsigned short*)w; w += (size_t)N * DH * 2;
    int*      csr    = (int*)w;      w += (size_t)E * 4;
    unsigned* ebuf   = (unsigned*)w; w += (size_t)E * 4;
    unsigned* bcnt   = (unsigned*)w; w += MAXNB * 4;
    unsigned* cursor = (unsigned*)w; w += 16;
    unsigned* bbase  = (unsigned*)w; w += MAXNB * 4;
    unsigned* bpos   = (unsigned*)w; w += MAXNB * 4;
    unsigned* off    = (unsigned*)w; w += (size_t)N * 4;
    unsigned* cnt    = (unsigned*)w; w += (size_t)N * 4;
    float*    nrm    = (float*)w;    w += (size_t)N * 4;
    unsigned short* Wt  = (unsigned short*)w; w += 3 * DH * DH * 2;
    unsigned short* Wft = (unsigned short*)w; w += 48 * DH * 2;
    float*    bfh    = (float*)w;    w += 64 * 4;

    const int gC = (E + CH - 1) / CH;

    hipMemsetAsync(bcnt, 0, MAXNB * 4 + 16, stream);   // bcnt + cursor
    bucket_hist   <<<gC, 256, 0, stream>>>(dst, E, bcnt);
    bucket_alloc  <<<(NB + 255) / 256, 256, 0, stream>>>(bcnt, bbase, bpos, cursor, NB);
    bucket_scatter<<<gC, 256, 0, stream>>>(src, dst, E, bpos, ebuf);
    bucket_csr    <<<NB, 256, 0, stream>>>(ebuf, bbase, bcnt, off, cnt, nrm, csr, N);

    cast_x<<<((N * DH / 4) + 255) / 256, 256, 0, stream>>>(x, xb, N * DH / 4);
    cast_w<<<(3 * DH * DH + 255) / 256, 256, 0, stream>>>(W1, W2, W3, Wt);
    fuse_w<<<(48 * DH + 48 + 255) / 256, 256, 0, stream>>>(Wp1, bp1, Wp2, bp2, Wft, bfh);

    const int gG = (N + 127) / 128;
    const int gA = (N + 15) / 16;

    gemm_mfma<<<gG, 256, 0, stream>>>(xb, Wt,              nrm, Ab, N);
    aggregate<<<gA, 256, 0, stream>>>((const uint4*)Ab, csr, off, cnt, nrm, b1, Bb, N);
    gemm_mfma<<<gG, 256, 0, stream>>>(Bb, Wt + DH * DH,     nrm, Ab, N);
    aggregate<<<gA, 256, 0, stream>>>((const uint4*)Ab, csr, off, cnt, nrm, b2, Bb, N);
    gemm_mfma<<<gG, 256, 0, stream>>>(Bb, Wt + 2 * DH * DH, nrm, Ab, N);
    aggregate<<<gA, 256, 0, stream>>>((const uint4*)Ab, csr, off, cnt, nrm, b3, Bb, N);

    final_mfma<<<(N + 63) / 64, 256, 0, stream>>>(Bb, Wft, bfh, out, N);
}